// Round 2
// baseline (195.668 us; speedup 1.0000x reference)
//
#include <hip/hip_runtime.h>

// AttentionBlock: B=8, C=128, H=W=128, GROUPS=8, HEADS=8, HEAD_DIM=16
// Pipeline: stats -> prep(fold GN into conv_in) -> gemm1+scores -> softmax+w_eff -> gemm1(recompute)+gemm2+residual
// R1 fix: Sg workspace was sized 2048 but indexed (b*8+h)*256 -> 16384 floats;
//         sA/vA/weff were being clobbered by K2's atomics. Re-layout ws only.

#define NPOS 16384          // 128*128 spatial
#define PITCH 136           // LDS row pitch in ushorts (16B-aligned rows, conflict-friendly)

typedef short short8 __attribute__((ext_vector_type(8)));   // 8 bf16 (4 VGPRs)
typedef float f32x4 __attribute__((ext_vector_type(4)));

__device__ __forceinline__ unsigned short f2bf(float f) {
    union { float f; unsigned u; } v; v.f = f;
    unsigned r = (v.u + 0x7fffu + ((v.u >> 16) & 1u)) >> 16;
    return (unsigned short)r;
}

// ---------------- K1: per-(b,g) sum / sumsq ----------------
__global__ __launch_bounds__(256) void k_stats(const float* __restrict__ x,
                                               float* __restrict__ stats) {
    // Each block: one 16384-float segment; 16 segments per (b,g) (contiguous).
    const float4* p = (const float4*)(x + (size_t)blockIdx.x * 16384);
    int t = threadIdx.x;
    float s1 = 0.f, s2 = 0.f;
#pragma unroll
    for (int j = 0; j < 16; ++j) {
        float4 v = p[t + j * 256];
        s1 += v.x + v.y + v.z + v.w;
        s2 += v.x * v.x + v.y * v.y + v.z * v.z + v.w * v.w;
    }
    for (int off = 32; off; off >>= 1) {
        s1 += __shfl_down(s1, off);
        s2 += __shfl_down(s2, off);
    }
    __shared__ float r1[4], r2[4];
    int wv = t >> 6;
    if ((t & 63) == 0) { r1[wv] = s1; r2[wv] = s2; }
    __syncthreads();
    if (t == 0) {
        s1 = r1[0] + r1[1] + r1[2] + r1[3];
        s2 = r2[0] + r2[1] + r2[2] + r2[3];
        int bg = blockIdx.x >> 4;
        atomicAdd(&stats[bg * 2 + 0], s1);
        atomicAdd(&stats[bg * 2 + 1], s2);
    }
}

// ---------------- K1b: fold GN into per-batch scale s[c] and bias v[c] ----------------
__global__ __launch_bounds__(128) void k_prep(const float* __restrict__ stats,
                                              const float* __restrict__ gn_w,
                                              const float* __restrict__ gn_b,
                                              const float* __restrict__ w_in,
                                              const float* __restrict__ b_in,
                                              float* __restrict__ sA,
                                              float* __restrict__ vA) {
    int b = blockIdx.x, c = threadIdx.x;
    int g = c >> 4;
    float s1 = stats[(b * 8 + g) * 2 + 0];
    float s2 = stats[(b * 8 + g) * 2 + 1];
    const float invN = 1.0f / 262144.0f;   // 16 ch * 16384 pos
    float mean = s1 * invN;
    float var = s2 * invN - mean * mean;
    float rstd = rsqrtf(var + 1e-5f);
    float s = gn_w[c] * rstd;
    float tt = gn_b[c] - mean * s;
    __shared__ float tl[128];
    tl[c] = tt;
    sA[b * 128 + c] = s;
    __syncthreads();
    float v = b_in[c];
    const float* wr = w_in + c * 128;
#pragma unroll 8
    for (int k = 0; k < 128; ++k) v += wr[k] * tl[k];
    vA[b * 128 + c] = v;
}

// ---------------- K2: h1 = (w_in*s)@x + v ; partial S = H H^T (atomics) ----------------
__global__ __launch_bounds__(256, 2) void k_gemm1_scores(const float* __restrict__ x,
                                                         const float* __restrict__ w_in,
                                                         const float* __restrict__ sA,
                                                         const float* __restrict__ vA,
                                                         float* __restrict__ Sg) {
    __shared__ unsigned short As[128 * PITCH];
    __shared__ unsigned short Xt[128 * PITCH];
    __shared__ float v_s[128];

    const int t = threadIdx.x;
    const int lane = t & 63, wv = t >> 6;
    const int q = lane >> 4, i16 = lane & 15;
    const int b = blockIdx.x >> 7;
    const int p0 = (blockIdx.x & 127) << 7;

    if (t < 128) v_s[t] = vA[b * 128 + t];

    // stage A = bf16(w_in * s_b)
    {
        const float4* w4 = (const float4*)w_in;
        const float4* s4 = (const float4*)(sA + b * 128);
#pragma unroll
        for (int i = 0; i < 16; ++i) {
            int idx = t + i * 256;        // float4 index over 128x128
            int c = idx >> 5, k4 = idx & 31;
            float4 w = w4[idx];
            float4 s = s4[k4];
            ushort4 o;
            o.x = f2bf(w.x * s.x); o.y = f2bf(w.y * s.y);
            o.z = f2bf(w.z * s.z); o.w = f2bf(w.w * s.w);
            *(ushort4*)&As[c * PITCH + k4 * 4] = o;
        }
    }
    // stage Xt[p][k] = bf16(x[k][p0+p])  (transpose)
    {
        const float* xb = x + (size_t)b * (128 * NPOS) + p0;
#pragma unroll
        for (int i = 0; i < 16; ++i) {
            int p = ((i & 1) << 6) + lane;
            int kq = (wv << 3) + (i >> 1);
            const float* col = xb + (size_t)(kq * 4) * NPOS + p;
            float a0 = col[0];
            float a1 = col[NPOS];
            float a2 = col[2 * NPOS];
            float a3 = col[3 * NPOS];
            ushort4 o; o.x = f2bf(a0); o.y = f2bf(a1); o.z = f2bf(a2); o.w = f2bf(a3);
            *(ushort4*)&Xt[p * PITCH + kq * 4] = o;
        }
    }
    __syncthreads();

    f32x4 acc[2][8];
#pragma unroll
    for (int a = 0; a < 2; ++a)
#pragma unroll
        for (int pt = 0; pt < 8; ++pt) acc[a][pt] = (f32x4){0.f, 0.f, 0.f, 0.f};

#pragma unroll
    for (int ks = 0; ks < 4; ++ks) {
        short8 a0 = *(const short8*)&As[(wv * 32 + i16) * PITCH + ks * 32 + q * 8];
        short8 a1 = *(const short8*)&As[(wv * 32 + 16 + i16) * PITCH + ks * 32 + q * 8];
#pragma unroll
        for (int pt = 0; pt < 8; ++pt) {
            short8 bb = *(const short8*)&Xt[(pt * 16 + i16) * PITCH + ks * 32 + q * 8];
            acc[0][pt] = __builtin_amdgcn_mfma_f32_16x16x32_bf16(a0, bb, acc[0][pt], 0, 0, 0);
            acc[1][pt] = __builtin_amdgcn_mfma_f32_16x16x32_bf16(a1, bb, acc[1][pt], 0, 0, 0);
        }
    }
    __syncthreads();            // Xt dead -> reuse as Hs[c][p]

    unsigned short* Hs = Xt;
#pragma unroll
    for (int a = 0; a < 2; ++a) {
        int cbase = wv * 32 + a * 16 + q * 4;
#pragma unroll
        for (int pt = 0; pt < 8; ++pt) {
            int p = pt * 16 + i16;
#pragma unroll
            for (int r = 0; r < 4; ++r) {
                int c = cbase + r;
                Hs[c * PITCH + p] = f2bf(acc[a][pt][r] + v_s[c]);
            }
        }
    }
    __syncthreads();

    // S partial: wave wv handles heads 2wv, 2wv+1 ; A==B frag (H H^T)
#pragma unroll
    for (int hh = 0; hh < 2; ++hh) {
        int h = wv * 2 + hh;
        f32x4 sacc = (f32x4){0.f, 0.f, 0.f, 0.f};
#pragma unroll
        for (int ks = 0; ks < 4; ++ks) {
            short8 f = *(const short8*)&Hs[(h * 16 + i16) * PITCH + ks * 32 + q * 8];
            sacc = __builtin_amdgcn_mfma_f32_16x16x32_bf16(f, f, sacc, 0, 0, 0);
        }
        float* sg = Sg + (b * 8 + h) * 256;
#pragma unroll
        for (int r = 0; r < 4; ++r)
            atomicAdd(&sg[(q * 4 + r) * 16 + i16], sacc[r]);
    }
}

// ---------------- K3: softmax + fold into w_eff[b] = w_out @ blockdiag(W) ----------------
__global__ __launch_bounds__(256) void k_softmax_weff(const float* __restrict__ Sg,
                                                      const float* __restrict__ w_out,
                                                      float* __restrict__ weff) {
    int b = blockIdx.x, t = threadIdx.x;
    __shared__ float W[2048];
    if (t < 128) {
        const float* row = Sg + b * 2048 + t * 16;
        float v[16];
        float m = -1e30f;
#pragma unroll
        for (int j = 0; j < 16; ++j) { v[j] = row[j] * 0.25f; m = fmaxf(m, v[j]); }
        float sum = 0.f;
#pragma unroll
        for (int j = 0; j < 16; ++j) { v[j] = __expf(v[j] - m); sum += v[j]; }
        float inv = 1.0f / sum;
#pragma unroll
        for (int j = 0; j < 16; ++j) W[t * 16 + j] = v[j] * inv;
    }
    __syncthreads();
    float* wo = weff + b * 16384;
#pragma unroll 2
    for (int n = 0; n < 64; ++n) {
        int idx = t + n * 256;
        int c = idx >> 7, k = idx & 127;
        int h = k >> 4, j = k & 15;
        const float* wr = w_out + c * 128 + h * 16;
        const float* Wr = W + h * 256 + j;
        float a = 0.f;
#pragma unroll
        for (int i = 0; i < 16; ++i) a += wr[i] * Wr[i * 16];
        wo[idx] = a;
    }
}

// ---------------- K4: recompute h1, out = x + b_out + w_eff @ h1 ----------------
__global__ __launch_bounds__(256, 2) void k_attn_out(const float* __restrict__ x,
                                                     const float* __restrict__ w_in,
                                                     const float* __restrict__ sA,
                                                     const float* __restrict__ vA,
                                                     const float* __restrict__ weff,
                                                     const float* __restrict__ b_out,
                                                     float* __restrict__ out) {
    __shared__ unsigned short As[128 * PITCH];
    __shared__ unsigned short Xt[128 * PITCH];
    __shared__ float v_s[128];
    __shared__ float bo_s[128];

    const int t = threadIdx.x;
    const int lane = t & 63, wv = t >> 6;
    const int q = lane >> 4, i16 = lane & 15;
    const int b = blockIdx.x >> 7;
    const int p0 = (blockIdx.x & 127) << 7;

    if (t < 128) { v_s[t] = vA[b * 128 + t]; bo_s[t] = b_out[t]; }

    const float* xb = x + (size_t)b * (128 * NPOS) + p0;

    // stage A1 = bf16(w_in * s_b)
    {
        const float4* w4 = (const float4*)w_in;
        const float4* s4 = (const float4*)(sA + b * 128);
#pragma unroll
        for (int i = 0; i < 16; ++i) {
            int idx = t + i * 256;
            int c = idx >> 5, k4 = idx & 31;
            float4 w = w4[idx];
            float4 s = s4[k4];
            ushort4 o;
            o.x = f2bf(w.x * s.x); o.y = f2bf(w.y * s.y);
            o.z = f2bf(w.z * s.z); o.w = f2bf(w.w * s.w);
            *(ushort4*)&As[c * PITCH + k4 * 4] = o;
        }
    }
    // stage Xt[p][k] = bf16(x[k][p0+p])
    {
#pragma unroll
        for (int i = 0; i < 16; ++i) {
            int p = ((i & 1) << 6) + lane;
            int kq = (wv << 3) + (i >> 1);
            const float* col = xb + (size_t)(kq * 4) * NPOS + p;
            float a0 = col[0];
            float a1 = col[NPOS];
            float a2 = col[2 * NPOS];
            float a3 = col[3 * NPOS];
            ushort4 o; o.x = f2bf(a0); o.y = f2bf(a1); o.z = f2bf(a2); o.w = f2bf(a3);
            *(ushort4*)&Xt[p * PITCH + kq * 4] = o;
        }
    }
    __syncthreads();

    f32x4 acc[2][8];
#pragma unroll
    for (int a = 0; a < 2; ++a)
#pragma unroll
        for (int pt = 0; pt < 8; ++pt) acc[a][pt] = (f32x4){0.f, 0.f, 0.f, 0.f};

#pragma unroll
    for (int ks = 0; ks < 4; ++ks) {
        short8 a0 = *(const short8*)&As[(wv * 32 + i16) * PITCH + ks * 32 + q * 8];
        short8 a1 = *(const short8*)&As[(wv * 32 + 16 + i16) * PITCH + ks * 32 + q * 8];
#pragma unroll
        for (int pt = 0; pt < 8; ++pt) {
            short8 bb = *(const short8*)&Xt[(pt * 16 + i16) * PITCH + ks * 32 + q * 8];
            acc[0][pt] = __builtin_amdgcn_mfma_f32_16x16x32_bf16(a0, bb, acc[0][pt], 0, 0, 0);
            acc[1][pt] = __builtin_amdgcn_mfma_f32_16x16x32_bf16(a1, bb, acc[1][pt], 0, 0, 0);
        }
    }
    __syncthreads();   // Xt(x) and As(w_in) dead

    // h1 -> Xt[p][c]  (bf16, +v)
#pragma unroll
    for (int a = 0; a < 2; ++a) {
        int cb = wv * 32 + a * 16 + q * 4;
#pragma unroll
        for (int pt = 0; pt < 8; ++pt) {
            int p = pt * 16 + i16;
            ushort4 o;
            o.x = f2bf(acc[a][pt][0] + v_s[cb + 0]);
            o.y = f2bf(acc[a][pt][1] + v_s[cb + 1]);
            o.z = f2bf(acc[a][pt][2] + v_s[cb + 2]);
            o.w = f2bf(acc[a][pt][3] + v_s[cb + 3]);
            *(ushort4*)&Xt[p * PITCH + cb] = o;
        }
    }
    // restage A2 = bf16(w_eff[b])
    {
        const float4* w4 = (const float4*)(weff + b * 16384);
#pragma unroll
        for (int i = 0; i < 16; ++i) {
            int idx = t + i * 256;
            int c = idx >> 5, k4 = idx & 31;
            float4 w = w4[idx];
            ushort4 o;
            o.x = f2bf(w.x); o.y = f2bf(w.y); o.z = f2bf(w.z); o.w = f2bf(w.w);
            *(ushort4*)&As[c * PITCH + k4 * 4] = o;
        }
    }
    __syncthreads();

    // GEMM2: out_acc = w_eff @ h1
#pragma unroll
    for (int a = 0; a < 2; ++a)
#pragma unroll
        for (int pt = 0; pt < 8; ++pt) acc[a][pt] = (f32x4){0.f, 0.f, 0.f, 0.f};

#pragma unroll
    for (int ks = 0; ks < 4; ++ks) {
        short8 a0 = *(const short8*)&As[(wv * 32 + i16) * PITCH + ks * 32 + q * 8];
        short8 a1 = *(const short8*)&As[(wv * 32 + 16 + i16) * PITCH + ks * 32 + q * 8];
#pragma unroll
        for (int pt = 0; pt < 8; ++pt) {
            short8 bb = *(const short8*)&Xt[(pt * 16 + i16) * PITCH + ks * 32 + q * 8];
            acc[0][pt] = __builtin_amdgcn_mfma_f32_16x16x32_bf16(a0, bb, acc[0][pt], 0, 0, 0);
            acc[1][pt] = __builtin_amdgcn_mfma_f32_16x16x32_bf16(a1, bb, acc[1][pt], 0, 0, 0);
        }
    }

    // epilogue: out = acc + b_out + x
    float* ob = out + (size_t)b * (128 * NPOS) + p0;
#pragma unroll
    for (int a = 0; a < 2; ++a) {
        int cb = wv * 32 + a * 16 + q * 4;
#pragma unroll
        for (int pt = 0; pt < 8; ++pt) {
            int p = pt * 16 + i16;
#pragma unroll
            for (int r = 0; r < 4; ++r) {
                int c = cb + r;
                ob[(size_t)c * NPOS + p] = acc[a][pt][r] + bo_s[c] + xb[(size_t)c * NPOS + p];
            }
        }
    }
}

extern "C" void kernel_launch(void* const* d_in, const int* in_sizes, int n_in,
                              void* d_out, int out_size, void* d_ws, size_t ws_size,
                              hipStream_t stream) {
    const float* x    = (const float*)d_in[0];
    const float* gn_w = (const float*)d_in[1];
    const float* gn_b = (const float*)d_in[2];
    const float* w_in = (const float*)d_in[3];
    const float* b_in = (const float*)d_in[4];
    const float* w_out= (const float*)d_in[5];
    const float* b_out= (const float*)d_in[6];
    float* out = (float*)d_out;

    float* ws    = (float*)d_ws;
    float* stats = ws;              // 128 floats
    float* Sg    = ws + 128;        // 16384 floats: (b*8+h)*256, b<8
    float* sA    = ws + 16512;      // 1024 floats
    float* vA    = ws + 17536;      // 1024 floats
    float* weff  = ws + 18560;      // 131072 floats  (total ws use ~598 KB)

    hipMemsetAsync(d_ws, 0, (128 + 16384) * sizeof(float), stream);
    k_stats<<<dim3(1024), dim3(256), 0, stream>>>(x, stats);
    k_prep<<<dim3(8), dim3(128), 0, stream>>>(stats, gn_w, gn_b, w_in, b_in, sA, vA);
    k_gemm1_scores<<<dim3(1024), dim3(256), 0, stream>>>(x, w_in, sA, vA, Sg);
    k_softmax_weff<<<dim3(8), dim3(256), 0, stream>>>(Sg, w_out, weff);
    k_attn_out<<<dim3(1024), dim3(256), 0, stream>>>(x, w_in, sA, vA, weff, b_out, out);
}